// Round 11
// baseline (126.970 us; speedup 1.0000x reference)
//
#include <hip/hip_runtime.h>

// out[n,c,p,y,x] = in1[n,c,y,x] - zpad(in2)[n,c, y+i-3, x+j-3],  p = i*7+j
// N=8, C=32, H=W=112 -> out [8,32,49,112,112] fp32 (629 MB write, 25.7 MB read).
//
// R10 = R5 (phase-separated, LDS-staged, 1 block/CU, PLANE-MAJOR store order)
// with ONE change: nontemporal stores. Completes the (order x store-type)
// matrix: interleaved/plain 128.6-129.6, interleaved/nt 123.9-124.8,
// plane-major/plain 129.1, plane-major/nt = THIS. Mechanism: nt bypasses L2,
// so the HBM-side drain sees raw program store order -- contiguity should
// matter for nt where it was null for plain (L2 reorders plain stores).
// Ledger: R0 134.7, R1 172 (confounded), R2 249, R3 128.6, R4 129.6,
// R5 129.1, R6 234.9, R7 124.8, R8 131.8, R9 123.9 (best).

#define HW     112
#define PLANE  12544           // 112*112
#define KK     49
#define NC_TOT 256
#define PITCH  120             // LDS row pitch: 4 zero-pad + 112 data + 4 zero-pad
#define ZROW   112             // all-zero row for out-of-range y
#define LDS_F  ((HW + 1) * PITCH)   // 113*120 = 13560 floats = 54240 B

typedef float f4 __attribute__((ext_vector_type(4)));

__global__ __launch_bounds__(1024) void sub2_kernel(
    const float* __restrict__ in1,
    const float* __restrict__ in2,
    float* __restrict__ out)
{
    __shared__ float s2[LDS_F];

    const int nc = blockIdx.x;          // 0..255, one per CU
    const int t  = threadIdx.x;         // 0..1023

    const float* a_pl = in1 + (size_t)nc * PLANE;
    const float* b_pl = in2 + (size_t)nc * PLANE;
    float*       o_nc = out + (size_t)nc * KK * PLANE;

    // ---- phase 1a: in1 plane -> registers (position sets e = t + 1024*k) ----
    const f4 a0 = *reinterpret_cast<const f4*>(a_pl + 4 * t);
    const f4 a1 = *reinterpret_cast<const f4*>(a_pl + 4 * (t + 1024));
    const f4 a2 = *reinterpret_cast<const f4*>(a_pl + 4 * (t + 2048));
    f4 a3 = {0.f, 0.f, 0.f, 0.f};
    const bool tail = (t < 64);
    if (tail) a3 = *reinterpret_cast<const f4*>(a_pl + 4 * (t + 3072));

    // ---- phase 1b: zero LDS, then stage in2 plane ----
    {
        const f4 z = {0.f, 0.f, 0.f, 0.f};
        #pragma unroll
        for (int k = 0; k < 4; ++k) {
            const int s = t + 1024 * k;
            if (s < LDS_F / 4) reinterpret_cast<f4*>(s2)[s] = z;
        }
    }
    __syncthreads();
    #pragma unroll
    for (int k = 0; k < 4; ++k) {
        const int s = t + 1024 * k;          // f4 slot: row r, col c
        if (s < 28 * HW) {
            const int r = s / 28;
            const int c = s - r * 28;
            *reinterpret_cast<f4*>(&s2[r * PITCH + 4 + 4 * c]) =
                *reinterpret_cast<const f4*>(b_pl + r * HW + 4 * c);
        }
    }
    __syncthreads();

    // position decode per set (e_k = t + 1024k, float index 4*e_k)
    int yk[4], xk[4];
    #pragma unroll
    for (int k = 0; k < 4; ++k) {
        const int e = t + 1024 * k;
        yk[k] = (4 * e) / HW;
        xk[k] = 4 * e - yk[k] * HW;
    }

    float* const ob0 = o_nc + 4 * (size_t)t;
    float* const ob1 = o_nc + 4 * (size_t)(t + 1024);
    float* const ob2 = o_nc + 4 * (size_t)(t + 2048);
    float* const ob3 = o_nc + 4 * (size_t)(t + 3072);

    // ---- phase 2: plane-major nontemporal stores ----
    #pragma unroll
    for (int i = 0; i < 7; ++i) {
        // window wf[k][m] = in2 value at x-coord xk-4+m, row yk+i-3 (clamped)
        float wf0[12], wf1[12], wf2[12], wf3[12];
        {
            #pragma unroll
            for (int k = 0; k < 3; ++k) {
                const int iy  = yk[k] + i - 3;
                const int row = ((unsigned)iy < HW) ? iy : ZROW;
                const float* wr = s2 + row * PITCH + xk[k];  // = padded x0-4
                const f4 w0 = *reinterpret_cast<const f4*>(wr);
                const f4 w1 = *reinterpret_cast<const f4*>(wr + 4);
                const f4 w2 = *reinterpret_cast<const f4*>(wr + 8);
                float* wf = (k == 0) ? wf0 : (k == 1) ? wf1 : wf2;
                wf[0]=w0.x; wf[1]=w0.y; wf[2] =w0.z; wf[3] =w0.w;
                wf[4]=w1.x; wf[5]=w1.y; wf[6] =w1.z; wf[7] =w1.w;
                wf[8]=w2.x; wf[9]=w2.y; wf[10]=w2.z; wf[11]=w2.w;
            }
            if (tail) {
                const int iy  = yk[3] + i - 3;
                const int row = ((unsigned)iy < HW) ? iy : ZROW;
                const float* wr = s2 + row * PITCH + xk[3];
                const f4 w0 = *reinterpret_cast<const f4*>(wr);
                const f4 w1 = *reinterpret_cast<const f4*>(wr + 4);
                const f4 w2 = *reinterpret_cast<const f4*>(wr + 8);
                wf3[0]=w0.x; wf3[1]=w0.y; wf3[2] =w0.z; wf3[3] =w0.w;
                wf3[4]=w1.x; wf3[5]=w1.y; wf3[6] =w1.z; wf3[7] =w1.w;
                wf3[8]=w2.x; wf3[9]=w2.y; wf3[10]=w2.z; wf3[11]=w2.w;
            }
        }

        #pragma unroll
        for (int j = 0; j < 7; ++j) {
            const size_t po = (size_t)(i * 7 + j) * PLANE;
            f4 r;
            r.x = a0.x - wf0[j + 1];
            r.y = a0.y - wf0[j + 2];
            r.z = a0.z - wf0[j + 3];
            r.w = a0.w - wf0[j + 4];
            __builtin_nontemporal_store(r, reinterpret_cast<f4*>(ob0 + po));
            r.x = a1.x - wf1[j + 1];
            r.y = a1.y - wf1[j + 2];
            r.z = a1.z - wf1[j + 3];
            r.w = a1.w - wf1[j + 4];
            __builtin_nontemporal_store(r, reinterpret_cast<f4*>(ob1 + po));
            r.x = a2.x - wf2[j + 1];
            r.y = a2.y - wf2[j + 2];
            r.z = a2.z - wf2[j + 3];
            r.w = a2.w - wf2[j + 4];
            __builtin_nontemporal_store(r, reinterpret_cast<f4*>(ob2 + po));
            if (tail) {
                r.x = a3.x - wf3[j + 1];
                r.y = a3.y - wf3[j + 2];
                r.z = a3.z - wf3[j + 3];
                r.w = a3.w - wf3[j + 4];
                __builtin_nontemporal_store(r, reinterpret_cast<f4*>(ob3 + po));
            }
        }
    }
}

extern "C" void kernel_launch(void* const* d_in, const int* in_sizes, int n_in,
                              void* d_out, int out_size, void* d_ws, size_t ws_size,
                              hipStream_t stream) {
    const float* in1 = (const float*)d_in[0];
    const float* in2 = (const float*)d_in[1];
    float* out = (float*)d_out;

    sub2_kernel<<<NC_TOT, 1024, 0, stream>>>(in1, in2, out);
}

// Round 12
// 124.966 us; speedup vs baseline: 1.0160x; 1.0160x over previous
//
#include <hip/hip_runtime.h>

// out[n,c,p,y,x] = in1[n,c,y,x] - zpad(in2)[n,c, y+i-3, x+j-3],  p = i*7+j
// N=8, C=32, H=W=112 -> out [8,32,49,112,112] fp32 (629 MB write, ~30 MB read).
//
// FINAL = R9 (best: 123.9 us = 5.29 TB/s): R3 LDS-strip skeleton + nt stores
// + XCD-contiguous nc mapping. Full ablation ledger (single-change each):
//   store order interleaved/plane-major/grid-stride: 123.9 / 127-129 / 235
//   nt store +3%; nt load -6%; LDS staging +4.5%; phase separation null;
//   XCD nc-locality +0.7%; occupancy 448x4/CU ~= 1024x1/CU; plane-block -25%+.
// Remaining gap vs fill-kernel pure-write calibration (6.6-6.9 TB/s) is
// intrinsic: mixed read stream + read/write turnaround + ramp/tail on a
// 124 us dispatch. Declared roofline.

#define HW     112
#define PLANE  12544        // 112*112
#define KK     49
#define NC_TOT 256          // 8*32
#define YB     16           // output rows per block
#define LROWS  22           // YB + 6 halo rows
#define LDSW   132          // LDS row pitch: [0..7]=0pad, [8..119]=x, [120..131]=0pad

typedef float f4 __attribute__((ext_vector_type(4)));

__global__ __launch_bounds__(448) void sub2_kernel(
    const float* __restrict__ in1,
    const float* __restrict__ in2,
    float* __restrict__ out)
{
    __shared__ float smem[LROWS * LDSW];   // 11616 B

    // XCD-contiguous mapping: XCD = b%8 owns nc range [32*xcd, 32*xcd+32)
    const int b   = blockIdx.x;            // 0..1791
    const int xcd = b & 7;
    const int idx = b >> 3;                // 0..223
    const int ncl = idx / 7;               // 0..31
    const int yb  = idx - ncl * 7;         // 0..6
    const int nc  = xcd * 32 + ncl;
    const int y0  = yb * YB;
    const int tid = threadIdx.x;

    // zero all of smem
    {
        const f4 z = {0.f, 0.f, 0.f, 0.f};
        for (int i2 = tid; i2 < (LROWS * LDSW) / 4; i2 += 448)
            reinterpret_cast<f4*>(smem)[i2] = z;
    }
    __syncthreads();

    // stage in2 rows [y0-3, y0+18] into smem data region (28 f4 per row)
    const float* b_pl = in2 + (size_t)nc * PLANE;
    for (int i2 = tid; i2 < LROWS * 28; i2 += 448) {
        const int r  = i2 / 28;
        const int c  = i2 - r * 28;
        const int gy = y0 - 3 + r;
        if (gy >= 0 && gy < HW) {
            *reinterpret_cast<f4*>(&smem[r * LDSW + 8 + 4 * c]) =
                *reinterpret_cast<const f4*>(b_pl + gy * HW + 4 * c);
        }
    }
    __syncthreads();

    const int yl = tid / 28;               // 0..15
    const int x0 = (tid - yl * 28) * 4;    // 0..108
    const int y  = y0 + yl;

    const f4 a = *reinterpret_cast<const f4*>(
        in1 + (size_t)nc * PLANE + y * HW + x0);
    float* o_base = out + (size_t)nc * KK * PLANE + (size_t)y * HW + x0;

    #pragma unroll
    for (int i = 0; i < 7; ++i) {
        // window floats x0-4 .. x0+11 (16B-aligned ds_read_b128 x4)
        const float* wr = &smem[(yl + i) * LDSW + 4 + x0];
        const f4 w0 = *reinterpret_cast<const f4*>(wr);
        const f4 w1 = *reinterpret_cast<const f4*>(wr + 4);
        const f4 w2 = *reinterpret_cast<const f4*>(wr + 8);
        const f4 w3 = *reinterpret_cast<const f4*>(wr + 12);
        float wf[16];
        wf[0]=w0.x;  wf[1]=w0.y;  wf[2]=w0.z;  wf[3]=w0.w;
        wf[4]=w1.x;  wf[5]=w1.y;  wf[6]=w1.z;  wf[7]=w1.w;
        wf[8]=w2.x;  wf[9]=w2.y;  wf[10]=w2.z; wf[11]=w2.w;
        wf[12]=w3.x; wf[13]=w3.y; wf[14]=w3.z; wf[15]=w3.w;

        #pragma unroll
        for (int j = 0; j < 7; ++j) {
            f4 r;
            r.x = a.x - wf[j + 1];
            r.y = a.y - wf[j + 2];
            r.z = a.z - wf[j + 3];
            r.w = a.w - wf[j + 4];
            __builtin_nontemporal_store(
                r, reinterpret_cast<f4*>(o_base + (size_t)(i * 7 + j) * PLANE));
        }
    }
}

extern "C" void kernel_launch(void* const* d_in, const int* in_sizes, int n_in,
                              void* d_out, int out_size, void* d_ws, size_t ws_size,
                              hipStream_t stream) {
    const float* in1 = (const float*)d_in[0];
    const float* in2 = (const float*)d_in[1];
    float* out = (float*)d_out;

    const int blocks = NC_TOT * 7;   // 1792 = 8 XCDs * 224
    sub2_kernel<<<blocks, 448, 0, stream>>>(in1, in2, out);
}